// Round 6
// baseline (122.100 us; speedup 1.0000x reference)
//
#include <hip/hip_runtime.h>

// ---------------------------------------------------------------------------
// PolyDecoder via SYMMETRY FOLDING: polyfeats(z) has only 1287 distinct
// monomials (multisets of 8 vars, deg<=5) vs 37449 columns. Fold W's columns
// into buckets, then GEMM with K=1312 (41 MFMA steps).
//
// R6: fully-coalesced fold. R5's fold_gather (lane-per-bucket, random scalar
// 4B gathers, 19% occupancy, worst-bucket wave imbalance) was ~20 us. Now:
//   prep (fused, 733 blocks): blocks 0..585 transpose W -> WT16[37504][64]
//     f16 via LDS tiles (256B coalesced reads, 128B coalesced writes, pads
//     zeroed); blocks 586..732 = R5-verified setup_csr (bucket rank +
//     in-bucket multiset-permutation rank; no atomics, deterministic).
//   fold (328 blocks): WAVE per bucket, lane = output row n. Member k costs
//     one coalesced 128B load WT16[k][*]; every WT16 element read exactly
//     once overall (buckets partition k). 8-deep independent loads per
//     group. One f16 store per lane into the R5-verified Wt fragment slot.
//   poly_gemm: byte-identical to the R3/R5-verified kernel.
//
// Bucket order (shared by CSR & feature table): degree-major, within a
// degree lexicographic over ascending tuples d1<=...<=dd. Degree starts:
// buckets {0,1,9,45,165,495}, original k {0,1,9,73,585,4681}.
// Fragment conventions (identical to previous verified kernels):
//   A: row=lane&15, k=(lane>>4)*8+j ; B: col=lane&15, k=(lane>>4)*8+j
//   C/D: col=lane&15, row=(lane>>4)*4+reg
// ---------------------------------------------------------------------------

#define TOTAL_TERMS 37449
#define NBUCKET 1287
#define KPAD 1312            // 41 * 32
#define FSTRIDE 1320         // feats LDS stride in halves
#define SLOTS_PER_B 120      // 15 groups of 8; deg5 max cnt = 120
#define NTB 586              // transpose blocks: 586*64 = 37504 k-columns
#define CSRB 147             // csr blocks: 147*256 >= 37449
#define NGRP_OFF 0           // u16[1312]                     (2624 B)
#define SLOTS_OFF 4096       // u16[1287*120]                 (308880 B)
#define WT16_OFF 315392      // f16[37504*64]                 (4800512 B)
#define WT_OFFSET 5115904    // f16 fragments, 41*4096 B      (167936 B)

typedef _Float16 half8 __attribute__((ext_vector_type(8)));
typedef float f32x4 __attribute__((ext_vector_type(4)));

__device__ __constant__ int KSTART[6] = {0, 1, 9, 73, 585, 4681};
__device__ __constant__ int BSTART[6] = {0, 1, 9, 45, 165, 495};
// NTAB[m][c] = C(m+7-c, m) = #ascending tuples of length m with digits >= c
__device__ __constant__ int NTAB[5][8] = {
    {1, 1, 1, 1, 1, 1, 1, 1},
    {8, 7, 6, 5, 4, 3, 2, 1},
    {36, 28, 21, 15, 10, 6, 3, 1},
    {120, 84, 56, 35, 20, 10, 4, 1},
    {330, 210, 126, 70, 35, 15, 5, 1}};
__device__ __constant__ int FACT[6] = {1, 1, 2, 6, 24, 120};

// ---------------------------------------------------------------------------
// prep: blocks [0,NTB) transpose W (f32, row-major) -> WT16 (f16, k-major);
//       blocks [NTB, NTB+CSRB) build the CSR (R5-verified math, verbatim).
// ---------------------------------------------------------------------------
__global__ __launch_bounds__(256) void prep(const float* __restrict__ W,
                                            _Float16* __restrict__ WT16,
                                            unsigned short* __restrict__ ngrp,
                                            unsigned short* __restrict__ slots) {
    int tid = threadIdx.x;
    if (blockIdx.x < NTB) {
        // ---- transpose role: 64x64 tile via LDS ----
        __shared__ _Float16 lds[64][66];
        int lane = tid & 63;
        int nq   = tid >> 6;               // 0..3
        int kb   = blockIdx.x * 64;
        int k    = kb + lane;
#pragma unroll
        for (int r = 0; r < 16; ++r) {
            int n = r * 4 + nq;
            float v = (k < TOTAL_TERMS) ? W[(size_t)n * TOTAL_TERMS + k] : 0.f;
            lds[n][lane] = (_Float16)v;    // coalesced 256B read per row
        }
        __syncthreads();
#pragma unroll
        for (int r = 0; r < 16; ++r) {
            int kl = r * 4 + nq;
            WT16[(size_t)(kb + kl) * 64 + lane] = lds[lane][kl];  // 128B store
        }
        return;
    }

    // ---- CSR role (verbatim R5-verified) ----
    int kk = (blockIdx.x - NTB) * 256 + tid;
    if (kk >= TOTAL_TERMS) return;
    int k = kk;

    int d = 0;
#pragma unroll
    for (int i = 1; i <= 5; ++i)
        if (k >= KSTART[i]) d = i;
    int loc = k - KSTART[d];
    int dgo[5] = {0, 0, 0, 0, 0};              // original order, MSB-first
    for (int i = d - 1; i >= 0; --i) { dgo[i] = loc & 7; loc >>= 3; }

    // bucket: sort ascending, combinatorial rank
    int dg[5];
#pragma unroll
    for (int i = 0; i < 5; ++i) dg[i] = dgo[i];
    for (int i = 1; i < d; ++i) {              // insertion sort ascending
        int v = dg[i], j = i;
        while (j > 0 && dg[j - 1] > v) { dg[j] = dg[j - 1]; --j; }
        dg[j] = v;
    }
    int brank = 0, lo = 0;
    for (int i = 0; i < d; ++i) {
        int m = d - 1 - i;
        for (int c = lo; c < dg[i]; ++c) brank += NTAB[m][c];
        lo = dg[i];
    }
    int b = BSTART[d] + brank;

    // in-bucket position: multiset permutation lex rank of dgo
    int mult[8] = {0, 0, 0, 0, 0, 0, 0, 0};
    for (int i = 0; i < d; ++i) mult[dgo[i]]++;
    int D = 1;
#pragma unroll
    for (int c = 0; c < 8; ++c) D *= FACT[mult[c]];
    int cnt = FACT[d] / D;                     // multiset permutation count
    int r = 0;
    for (int i = 0; i < d; ++i) {
        int rem = d - 1 - i;
        for (int c = 0; c < dgo[i]; ++c)
            if (mult[c] > 0) r += FACT[rem] * mult[c] / D;  // exact
        D /= mult[dgo[i]];                     // fact[m]/fact[m-1] = m
        mult[dgo[i]]--;
    }

    slots[b * SLOTS_PER_B + r] = (unsigned short)k;
    if (r == 0) {                              // unique representative
        int ng = (cnt + 7) >> 3;
        ngrp[b] = (unsigned short)ng;
        for (int i = cnt; i < ng * 8; ++i)     // pad last group (<=7 writes)
            slots[b * SLOTS_PER_B + i] = 0xFFFFu;
    }
}

// ---------------------------------------------------------------------------
// fold: wave per bucket, lane = output row n. Grid 328 x 256 (= 1312 waves).
// Each group: 8 slot ids (one uint4), 8 coalesced 128B WT16 row loads.
// ---------------------------------------------------------------------------
__global__ __launch_bounds__(256) void fold(const _Float16* __restrict__ WT16,
                                            const float* __restrict__ bias,
                                            const unsigned short* __restrict__ ngrp,
                                            const unsigned short* __restrict__ slots,
                                            _Float16* __restrict__ Wt) {
    int lane = threadIdx.x & 63;       // = output row n
    int w    = threadIdx.x >> 6;
    int b    = blockIdx.x * 4 + w;     // [0, 1312)

    float s = 0.f;
    if (b < NBUCKET) {
        const unsigned short* sb = slots + (size_t)b * SLOTS_PER_B;
        int ng = ngrp[b];
        for (int gg = 0; gg < ng; ++gg) {
            uint4 sv = *(const uint4*)(sb + (size_t)gg * 8);  // 8 x u16
            unsigned ks[8];
            ks[0] = sv.x & 0xFFFFu; ks[1] = sv.x >> 16;
            ks[2] = sv.y & 0xFFFFu; ks[3] = sv.y >> 16;
            ks[4] = sv.z & 0xFFFFu; ks[5] = sv.z >> 16;
            ks[6] = sv.w & 0xFFFFu; ks[7] = sv.w >> 16;
            float v[8];
#pragma unroll
            for (int j = 0; j < 8; ++j)        // 8 independent coalesced loads
                v[j] = (ks[j] != 0xFFFFu)
                         ? (float)WT16[(size_t)ks[j] * 64 + lane] : 0.f;
            s += ((v[0] + v[1]) + (v[2] + v[3])) +
                 ((v[4] + v[5]) + (v[6] + v[7]));
        }
        if (b == 0) s += bias[lane];   // bias folds into const feature
    }
    // write folded element (col n=lane, k b) at its fragment position
    // (identical layout to R5-verified store)
    int ss = b >> 5, kk = b & 31, quad = kk >> 3, j = kk & 7;
    int fl = (lane & 15) + quad * 16;
    Wt[((size_t)((ss * 4 + (lane >> 4)) * 64 + fl)) * 8 + j] = (_Float16)s;
}

// ---------------------------------------------------------------------------
// Compile-time feature-expansion table: entry = parent | zdigit<<11 | dest<<15.
// Enumerates degrees 2..5 over ascending multisets, per-degree padded to a
// multiple of 32 (pads write dump slot 1311, re-zeroed later).
// Padded counts {64,128,352,800} (real {36,120,330,792}), total 1344.
// ---------------------------------------------------------------------------
struct ATab {
    unsigned int t[1344];
    constexpr ATab() : t() {
        int last[1287] = {};
        last[0] = 0;
        for (int c = 0; c < 8; ++c) last[1 + c] = c;
        int starts[6] = {0, 1, 9, 45, 165, 495};
        int pcnt[6] = {0, 0, 64, 128, 352, 800};
        int pos = 0;
        for (int d = 2; d <= 5; ++d) {
            int ps = starts[d - 1], pe = starts[d];
            int dest = starts[d];
            int cnt = 0;
            for (int p = ps; p < pe; ++p)
                for (int c = last[p]; c < 8; ++c) {
                    last[dest] = c;
                    t[pos++] = (unsigned)p | ((unsigned)c << 11) |
                               ((unsigned)dest << 15);
                    ++dest; ++cnt;
                }
            for (; cnt < pcnt[d]; ++cnt)
                t[pos++] = 0u | (0u << 11) | (1311u << 15);
        }
    }
};
__device__ const ATab A_TAB{};

// 256 blocks x 16 rows. 8 waves: h = w&3 (16-col group), kh = w>>2 (K half,
// interleaved: wave kh does steps s = 2i+kh). K-halves merged via LDS.
__global__ __launch_bounds__(512) void poly_gemm(const float* __restrict__ z,
                                                 const _Float16* __restrict__ Wt,
                                                 float* __restrict__ out) {
    __shared__ _Float16 feats[16][FSTRIDE];
    __shared__ f32x4 sacc[4][64];
    int tid = threadIdx.x;
    int lane = tid & 63;
    int w = tid >> 6;
    int h = w & 3;
    int kh = w >> 2;
    int mb = blockIdx.x;                       // rows [mb*16, +16)

    // ---- B prologue: prefetch this wave's first 8 steps (s = 2i+kh) ----
    const char* gb = (const char*)Wt + (size_t)(h * 64 + lane) * 16
                   + (size_t)kh * 4096;        // +8192 per i
    half8 Bk[2][8];
#pragma unroll
    for (int i = 0; i < 8; ++i)
        Bk[0][i] = *(const half8*)(gb + (size_t)i * 8192);

    // ---- stage z -> deg0/deg1 features ----
    if (tid < 128) {
        int row = tid >> 3, c = tid & 7;
        float v = z[(size_t)(mb * 16 + row) * 8 + c];
        feats[row][1 + c] = (_Float16)v;
        if (c == 0) feats[row][0] = (_Float16)1.f;
    }

    // ---- feature expansion, degree by degree (parents strictly lower) ----
    int sub = tid & 31, row = tid >> 5;
    const int PS[4] = {0, 64, 192, 544};
    const int PTRIP[4] = {2, 4, 11, 25};
#pragma unroll
    for (int dd = 0; dd < 4; ++dd) {
        __syncthreads();
        int base = PS[dd] + sub;
#pragma unroll
        for (int e = 0; e < PTRIP[dd]; ++e) {
            unsigned v = A_TAB.t[base + (e << 5)];
            int p = v & 2047;
            int c = (v >> 11) & 15;
            int dst = v >> 15;
            feats[row][dst] = feats[row][p] * feats[row][1 + c];
        }
    }
    __syncthreads();
    if (sub < 25) feats[row][1287 + sub] = (_Float16)0.f;  // zero K-pad
    __syncthreads();

    // ---- GEMM: 41 steps split even/odd across kh; 21 (kh=0) / 20 (kh=1) ----
    f32x4 acc0 = {0.f, 0.f, 0.f, 0.f}, acc1 = {0.f, 0.f, 0.f, 0.f};
    int q = (lane >> 4) & 3;
    int arow = lane & 15;
    const _Float16* ap = &feats[arow][kh * 32 + q * 8];  // + i*64 per step

#define STEP(i, bank, slot)                                                    \
    {                                                                          \
        half8 av = *(const half8*)(ap + (i) * 64);                             \
        if ((i) & 1)                                                           \
            acc1 = __builtin_amdgcn_mfma_f32_16x16x32_f16(av, Bk[bank][slot],  \
                                                          acc1, 0, 0, 0);      \
        else                                                                   \
            acc0 = __builtin_amdgcn_mfma_f32_16x16x32_f16(av, Bk[bank][slot],  \
                                                          acc0, 0, 0, 0);      \
    }

    // group 0: compute i=0..7 from Bk[0], prefetch i=8..15 -> Bk[1]
#pragma unroll
    for (int i = 0; i < 8; ++i)
        Bk[1][i] = *(const half8*)(gb + (size_t)(8 + i) * 8192);
#pragma unroll
    for (int i = 0; i < 8; ++i) STEP(i, 0, i)
    // group 1: compute i=8..15 from Bk[1], prefetch i=16..19(+20) -> Bk[0]
#pragma unroll
    for (int i = 0; i < 4; ++i)
        Bk[0][i] = *(const half8*)(gb + (size_t)(16 + i) * 8192);
    if (kh == 0) Bk[0][4] = *(const half8*)(gb + (size_t)20 * 8192);
#pragma unroll
    for (int i = 8; i < 16; ++i) STEP(i, 1, i - 8)
    // tail: i=16..19, plus i=20 for kh==0
#pragma unroll
    for (int i = 16; i < 20; ++i) STEP(i, 0, i - 16)
    if (kh == 0) STEP(20, 0, 4)
#undef STEP

    f32x4 accf = acc0 + acc1;

    // ---- merge K halves, write out ----
    if (kh == 1) sacc[h][lane] = accf;
    __syncthreads();
    if (kh == 0) {
        accf += sacc[h][lane];
        int col = h * 16 + (lane & 15);
        int r0 = mb * 16 + q * 4;
#pragma unroll
        for (int r = 0; r < 4; ++r)
            out[(size_t)(r0 + r) * 64 + col] = accf[r];
    }
}

extern "C" void kernel_launch(void* const* d_in, const int* in_sizes, int n_in,
                              void* d_out, int out_size, void* d_ws, size_t ws_size,
                              hipStream_t stream) {
    (void)in_sizes; (void)n_in; (void)out_size; (void)ws_size;
    const float* z = (const float*)d_in[0];
    const float* W = (const float*)d_in[1];
    const float* b = (const float*)d_in[2];
    float* out = (float*)d_out;

    unsigned short* ngrp  = (unsigned short*)((char*)d_ws + NGRP_OFF);
    unsigned short* slots = (unsigned short*)((char*)d_ws + SLOTS_OFF);
    _Float16* WT16 = (_Float16*)((char*)d_ws + WT16_OFF);
    _Float16* Wt   = (_Float16*)((char*)d_ws + WT_OFFSET);   // 41*4096 B

    hipLaunchKernelGGL(prep, dim3(NTB + CSRB), dim3(256), 0, stream,
                       W, WT16, ngrp, slots);
    hipLaunchKernelGGL(fold, dim3(KPAD / 4), dim3(256), 0, stream,
                       WT16, b, ngrp, slots, Wt);
    hipLaunchKernelGGL(poly_gemm, dim3(256), dim3(512), 0, stream, z, Wt, out);
}

// Round 7
// 107.603 us; speedup vs baseline: 1.1347x; 1.1347x over previous
//
#include <hip/hip_runtime.h>

// ---------------------------------------------------------------------------
// PolyDecoder: out[4096,64] = polyfeats(z)[4096,37449] @ W^T + b
// f16 MFMA GEMM, A generated on the fly from registers; B double-banked in
// REGISTERS with 8-step-deep prefetch (~1300 cyc cover) — no barriers in the
// K-loop. Two-phase output (nontemporal partial stores + reduce), no atomics.
//
// R7: revert to the measured-best R1 chassis (92.9 us; folding pipeline
// rounds R5/R6 measured 100/122 vs predicted 80-85 with no counter
// visibility — abandoned). Two bounded tweaks vs R1:
//   (1) A-gen uses half8 * scalar broadcast (v_pk_mul_f16) — halves A-gen
//       VALU ops; bit-identical elementwise f16 math.
//   (2) all Wt B-prefetch loads are __builtin_nontemporal_load (150 MB/iter
//       read-once stream; don't thrash L2 vs part-writes).
//
// Padded K layout (32-granular; W padded with zeros):
//   kpad [0,8)=z | 8=const(bias folded) | [9,32)=0 | [32,96)=z^2 |
//   [96,608)=z^3 | [608,4704)=z^4 | [4704,37472)=z^5 | [37472,37504)=0
// step s = kpad/32: 0 deg<=1 | 1..2 deg2 | 3..18 deg3 | 19..146 deg4 |
//                   147..1170 deg5 | 1171 pad
//
// Grid (mb-major): (MBLK=32 m-blocks of 128 rows) x (KY=16) = 512 blocks
//   == exactly 2 blocks/CU on 256 CUs -> single dispatch round, no tail.
// Every block ky in [0,16) does a uniform 9-group pipeline + 1-2 extra steps:
//   groups 0..7: deg5 slice, s = 147 + 64*ky          (64 steps)
//   group  8:    deg4 slice, s = 19 + 8*ky            (8 steps)
//   extras:      s = ky, and s = 16+ky for ky < 3     (1-2 steps)
// Block: 4 waves; wave (g=w>>1, h=w&1): rows [g*64,+64) x cols [h*32,+32)
//   -> 8 mfma_f32_16x16x32_f16 / step; acc 4x2xf32x4 = 32 VGPR.
// B regs: Bk[2][16] half8 = 128 VGPR; ~210 total -> 2 waves/SIMD.
// ---------------------------------------------------------------------------

#define TOTAL_TERMS 37449
#define NSTEP 1172
#define MBLK 32
#define KY 16
#define OUT_ELEMS 262144            // 4096*64

typedef _Float16 half8 __attribute__((ext_vector_type(8)));
typedef float f32x4 __attribute__((ext_vector_type(4)));

// Coalesced tiled transpose W (f32, n-major) -> Wt (f16 fragments).
// Fragment element (s,nt,lane,j) = W[nt*16+(lane&15)][orig(s*32+(lane>>4)*8+j)]
__global__ __launch_bounds__(256) void convert_w(const float* __restrict__ W,
                                                 const float* __restrict__ bias,
                                                 _Float16* __restrict__ Wt) {
    __shared__ _Float16 lds[64][72];
    int tid  = threadIdx.x;
    int lane = tid & 63;
    int nq   = tid >> 6;               // 0..3
    int kb   = blockIdx.x * 64;
    int kp   = kb + lane;

    int o, mode;                       // 0=load W, 1=zero, 2=const+bias
    if (kp < 8)           { o = 1 + kp;            mode = 0; }
    else if (kp == 8)     { o = 0;                 mode = 2; }
    else if (kp < 32)     { o = 0;                 mode = 1; }
    else if (kp < 96)     { o = 9    + (kp - 32);  mode = 0; }
    else if (kp < 608)    { o = 73   + (kp - 96);  mode = 0; }
    else if (kp < 4704)   { o = 585  + (kp - 608); mode = 0; }
    else if (kp < 37472)  { o = 4681 + (kp - 4704);mode = 0; }
    else                  { o = 0;                 mode = 1; }

#pragma unroll
    for (int r = 0; r < 16; ++r) {
        int n = r * 4 + nq;
        const float* wrow = W + (size_t)n * TOTAL_TERMS;
        float v;
        if (mode == 1)      v = 0.f;
        else if (mode == 2) v = wrow[0] + bias[n];
        else                v = wrow[o];             // coalesced along lane
        lds[n][lane] = (_Float16)v;
    }
    __syncthreads();

    int quad = lane >> 4, l16 = lane & 15;
    int n = nq * 16 + l16;
#pragma unroll
    for (int sl = 0; sl < 2; ++sl) {
        int kk = sl * 32 + quad * 8;
        half8 hv;
#pragma unroll
        for (int j = 0; j < 8; ++j) hv[j] = lds[n][kk + j];
        int s = (kb >> 5) + sl;
        *(half8*)(Wt + ((size_t)(s * 4 + nq) * 64 + lane) * 8) = hv;  // coalesced
    }
}

__global__ __launch_bounds__(256, 2) void poly_gemm(const float* __restrict__ z,
                                                    const _Float16* __restrict__ Wt,
                                                    float* __restrict__ part,
                                                    float* __restrict__ out,
                                                    int use_atomic) {
    __shared__ __align__(16) _Float16 zm[128][8];   // sample-major
    __shared__ _Float16 zT[8][144];                 // digit-major

    int tid  = threadIdx.x;
    int lane = tid & 63;
    int w    = tid >> 6;
    int g    = w >> 1;                 // rows [g*64, g*64+64)
    int h    = w & 1;                  // cols [h*32, h*32+32)
    int mb   = blockIdx.x;
    int ky   = blockIdx.y;             // [0, 16) -- every block is uniform

    // Per-step B bytes: 4 frags x 1024 B; this wave reads frags 2h, 2h+1.
    const char* gb  = (const char*)Wt + (size_t)((147 + 64 * ky) * 4 + 2 * h) * 1024
                    + (size_t)lane * 16;                       // deg5 slice
    const char* gb4 = (const char*)Wt + (size_t)((19 + 8 * ky) * 4 + 2 * h) * 1024
                    + (size_t)lane * 16;                       // deg4 slice

    // Prologue: prefetch deg5 group 0 (8 steps) into bank 0 BEFORE z staging
    // so its latency overlaps the z loads + barrier.
    half8 Bk[2][16];
#pragma unroll
    for (int ii = 0; ii < 8; ++ii)
#pragma unroll
        for (int k = 0; k < 2; ++k)
            Bk[0][ii * 2 + k] = __builtin_nontemporal_load(
                (const half8*)(gb + ii * 4096 + k * 1024));

    if (tid < 128) {
        const float* zp = z + ((size_t)(mb * 128 + tid)) * 8;
        float4 a = *(const float4*)zp;
        float4 b4 = *(const float4*)(zp + 4);
        half8 hz;
        hz[0] = (_Float16)a.x;  hz[1] = (_Float16)a.y;
        hz[2] = (_Float16)a.z;  hz[3] = (_Float16)a.w;
        hz[4] = (_Float16)b4.x; hz[5] = (_Float16)b4.y;
        hz[6] = (_Float16)b4.z; hz[7] = (_Float16)b4.w;
        *(half8*)&zm[tid][0] = hz;
#pragma unroll
        for (int j = 0; j < 8; ++j) zT[j][tid] = hz[j];
    }
    __syncthreads();

    int quad = lane >> 4;
    int l16  = lane & 15;
    int mrow[4];
    half8 zv[4];
    _Float16 zq[4], zq4[4];
#pragma unroll
    for (int t = 0; t < 4; ++t) {
        mrow[t] = g * 64 + t * 16 + l16;
        zv[t]   = *(const half8*)&zm[mrow[t]][0];
        zq[t]   = zT[quad][mrow[t]];       // z[quad]
        zq4[t]  = zT[quad + 4][mrow[t]];   // z[quad+4]
    }

    f32x4 acc[4][2];
#pragma unroll
    for (int t = 0; t < 4; ++t)
#pragma unroll
        for (int k = 0; k < 2; ++k) acc[t][k] = (f32x4){0.f, 0.f, 0.f, 0.f};

    // d1 digit for both deg5 and deg4 slices of this ky: z[ky>>1]
    _Float16 a1[4];
#pragma unroll
    for (int t = 0; t < 4; ++t) a1[t] = zT[ky >> 1][mrow[t]];

    // ---- deg5 main: 8 groups (4 sc x 2 gp), bank = group & 1 ----
    for (int sc = 0; sc < 4; ++sc) {
        int rtop = (4 * ky + sc) & 7;                  // d2 digit
        _Float16 gz[4];
#pragma unroll
        for (int t = 0; t < 4; ++t) gz[t] = a1[t] * zT[rtop][mrow[t]];
#pragma unroll
        for (int gp = 0; gp < 2; ++gp) {
            // prefetch next 8-step group into the other bank; the 9th group
            // slot fetches the deg4 slice instead of running off the end
            const char* gn = (sc == 3 && gp == 1) ? gb4 : (gb + 32768);
#pragma unroll
            for (int ii = 0; ii < 8; ++ii)
#pragma unroll
                for (int k = 0; k < 2; ++k)
                    Bk[gp ^ 1][ii * 2 + k] = __builtin_nontemporal_load(
                        (const half8*)(gn + ii * 4096 + k * 1024));
            // compute 8 steps from current bank (all indices compile-time)
#pragma unroll
            for (int ii = 0; ii < 8; ++ii) {
                const int r3 = gp * 4 + (ii >> 1);
                half8 av[4];
#pragma unroll
                for (int t = 0; t < 4; ++t) {
                    _Float16 f = gz[t] * zv[t][r3] *
                                 ((ii & 1) ? zq4[t] : zq[t]);
                    av[t] = zv[t] * f;                 // v_pk_mul_f16 x4
                }
#pragma unroll
                for (int t = 0; t < 4; ++t)
#pragma unroll
                    for (int k = 0; k < 2; ++k)
                        acc[t][k] = __builtin_amdgcn_mfma_f32_16x16x32_f16(
                            av[t], Bk[gp][ii * 2 + k], acc[t][k], 0, 0, 0);
            }
            gb += 32768;
        }
    }

    // ---- deg4 group: 8 steps from bank 0; prefetch extra-step B -> bank 1 ----
    {
        const char* ge0 = (const char*)Wt + (size_t)(ky * 4 + 2 * h) * 1024
                        + (size_t)lane * 16;           // step s = ky
        Bk[1][0] = __builtin_nontemporal_load((const half8*)(ge0));
        Bk[1][1] = __builtin_nontemporal_load((const half8*)(ge0 + 1024));
        if (ky < 3) {                                  // step s = 16 + ky
            const char* ge1 = (const char*)Wt
                            + (size_t)((16 + ky) * 4 + 2 * h) * 1024
                            + (size_t)lane * 16;
            Bk[1][2] = __builtin_nontemporal_load((const half8*)(ge1));
            Bk[1][3] = __builtin_nontemporal_load((const half8*)(ge1 + 1024));
        }
        // deg4 digits: d1 = ky>>1 (a1), d2 = (ky&1)*4 + (ii>>1),
        //              d3 = quad + 4*(ii&1), d4 = e
        const int r3b = (ky & 1) * 4;
        _Float16 d2z[4][4];                            // static-index regs
#pragma unroll
        for (int j = 0; j < 4; ++j)
#pragma unroll
            for (int t = 0; t < 4; ++t) d2z[t][j] = zT[r3b + j][mrow[t]];
#pragma unroll
        for (int ii = 0; ii < 8; ++ii) {
            half8 av[4];
#pragma unroll
            for (int t = 0; t < 4; ++t) {
                _Float16 f = a1[t] * d2z[t][ii >> 1] *
                             ((ii & 1) ? zq4[t] : zq[t]);
                av[t] = zv[t] * f;                     // v_pk_mul_f16 x4
            }
#pragma unroll
            for (int t = 0; t < 4; ++t)
#pragma unroll
                for (int k = 0; k < 2; ++k)
                    acc[t][k] = __builtin_amdgcn_mfma_f32_16x16x32_f16(
                        av[t], Bk[0][ii * 2 + k], acc[t][k], 0, 0, 0);
        }
    }

    // ---- extra low-degree step(s): s = ky, plus s = 16+ky for ky < 3 ----
    {
        half8 av[4];
        if (ky == 0) {
            // s==0: deg<=1 (z | const | zeros)
#pragma unroll
            for (int t = 0; t < 4; ++t) {
                if (quad == 0)      av[t] = zv[t];
                else if (quad == 1) { av[t] = (half8){}; av[t][0] = (_Float16)1.f; }
                else                av[t] = (half8){};
            }
        } else if (ky < 3) {
            // s=1..2: deg2
            int r1 = (ky - 1) * 4 + quad;
#pragma unroll
            for (int t = 0; t < 4; ++t) {
                _Float16 f = zT[r1][mrow[t]];
                av[t] = zv[t] * f;
            }
        } else {
            // s=3..15: deg3, u = s-3
            int u = ky - 3;
            int r1 = u >> 1, r2 = ((u & 1) << 2) + quad;
#pragma unroll
            for (int t = 0; t < 4; ++t) {
                _Float16 f = zT[r1][mrow[t]] * zT[r2][mrow[t]];
                av[t] = zv[t] * f;
            }
        }
#pragma unroll
        for (int t = 0; t < 4; ++t)
#pragma unroll
            for (int k = 0; k < 2; ++k)
                acc[t][k] = __builtin_amdgcn_mfma_f32_16x16x32_f16(
                    av[t], Bk[1][k], acc[t][k], 0, 0, 0);

        if (ky < 3) {
            // s = 16+ky: deg3, u = 13+ky
            int u = 13 + ky;
            int r1 = u >> 1, r2 = ((u & 1) << 2) + quad;
#pragma unroll
            for (int t = 0; t < 4; ++t) {
                _Float16 f = zT[r1][mrow[t]] * zT[r2][mrow[t]];
                av[t] = zv[t] * f;
            }
#pragma unroll
            for (int t = 0; t < 4; ++t)
#pragma unroll
                for (int k = 0; k < 2; ++k)
                    acc[t][k] = __builtin_amdgcn_mfma_f32_16x16x32_f16(
                        av[t], Bk[1][2 + k], acc[t][k], 0, 0, 0);
        }
    }

    // epilogue: C/D layout col=lane&15, row=(lane>>4)*4+reg
    float* dstbase = use_atomic ? out : (part + (size_t)ky * OUT_ELEMS);
#pragma unroll
    for (int t = 0; t < 4; ++t) {
        int mbase = mb * 128 + g * 64 + t * 16 + quad * 4;
#pragma unroll
        for (int k = 0; k < 2; ++k) {
            int col = h * 32 + k * 16 + l16;
#pragma unroll
            for (int r = 0; r < 4; ++r) {
                size_t idx = (size_t)(mbase + r) * 64 + col;
                if (use_atomic) unsafeAtomicAdd(out + idx, acc[t][k][r]);
                else __builtin_nontemporal_store(acc[t][k][r], dstbase + idx);
            }
        }
    }
}

// Phase 2: out[i] = sum_ky part[ky][i]  (vectorized, nontemporal)
__global__ __launch_bounds__(256) void reduce_part(const float* __restrict__ part,
                                                   float* __restrict__ out) {
    int gid = blockIdx.x * 256 + threadIdx.x;      // 65536 float4s
    const f32x4* p4 = (const f32x4*)part;
    f32x4 s = (f32x4){0.f, 0.f, 0.f, 0.f};
#pragma unroll
    for (int j = 0; j < KY; ++j)
        s += __builtin_nontemporal_load(p4 + (size_t)j * (OUT_ELEMS / 4) + gid);
    __builtin_nontemporal_store(s, ((f32x4*)out) + gid);
}

extern "C" void kernel_launch(void* const* d_in, const int* in_sizes, int n_in,
                              void* d_out, int out_size, void* d_ws, size_t ws_size,
                              hipStream_t stream) {
    (void)in_sizes; (void)n_in;
    const float* z = (const float*)d_in[0];
    const float* W = (const float*)d_in[1];
    const float* b = (const float*)d_in[2];
    float* out = (float*)d_out;

    const size_t part_bytes = (size_t)KY * OUT_ELEMS * sizeof(float);  // 16 MB
    const size_t wt_bytes   = (size_t)(NSTEP + 16) * 2048 * sizeof(_Float16);
    const bool two_phase = ws_size >= part_bytes + wt_bytes;

    float* part;
    _Float16* Wt;
    if (two_phase) {
        part = (float*)d_ws;
        Wt   = (_Float16*)((char*)d_ws + part_bytes);
    } else {
        part = out;                    // unused in atomic mode
        Wt   = (_Float16*)d_ws;
    }

    if (!two_phase)
        hipMemsetAsync(d_out, 0, (size_t)out_size * sizeof(float), stream);
    hipLaunchKernelGGL(convert_w, dim3(NSTEP / 2), dim3(256), 0, stream, W, b, Wt);
    hipLaunchKernelGGL(poly_gemm, dim3(MBLK, KY), dim3(256), 0, stream,
                       z, Wt, part, out, two_phase ? 0 : 1);
    if (two_phase)
        hipLaunchKernelGGL(reduce_part, dim3(OUT_ELEMS / 4 / 256), dim3(256), 0,
                           stream, part, out);
}

// Round 8
// 93.581 us; speedup vs baseline: 1.3048x; 1.1498x over previous
//
#include <hip/hip_runtime.h>

// ---------------------------------------------------------------------------
// PolyDecoder: out[4096,64] = polyfeats(z)[4096,37449] @ W^T + b
// f16 MFMA GEMM, A generated on the fly from registers; B double-banked in
// REGISTERS with 8-step-deep prefetch (~1300 cyc cover) — no barriers in the
// K-loop. Two-phase output (nontemporal partial stores + reduce), no atomics.
//
// R8: revert R7's nontemporal B loads — Wt is read 32x (each ky-slice by all
// 32 mb-blocks), so nt demoted an L2-served stream to LLC/HBM re-fetches
// (R7 = 107.6 us vs R1 = 92.9). Keep R7's packed A-gen (half8 * scalar
// broadcast -> v_pk_mul_f16; halves A-gen VALU ops, bit-identical math).
//
// Padded K layout (32-granular; W padded with zeros):
//   kpad [0,8)=z | 8=const(bias folded) | [9,32)=0 | [32,96)=z^2 |
//   [96,608)=z^3 | [608,4704)=z^4 | [4704,37472)=z^5 | [37472,37504)=0
// step s = kpad/32: 0 deg<=1 | 1..2 deg2 | 3..18 deg3 | 19..146 deg4 |
//                   147..1170 deg5 | 1171 pad
//
// Grid (mb-major): (MBLK=32 m-blocks of 128 rows) x (KY=16) = 512 blocks
//   == exactly 2 blocks/CU on 256 CUs -> single dispatch round, no tail.
// Every block ky in [0,16) does a uniform 9-group pipeline + 1-2 extra steps:
//   groups 0..7: deg5 slice, s = 147 + 64*ky          (64 steps)
//   group  8:    deg4 slice, s = 19 + 8*ky            (8 steps)
//   extras:      s = ky, and s = 16+ky for ky < 3     (1-2 steps)
// Block: 4 waves; wave (g=w>>1, h=w&1): rows [g*64,+64) x cols [h*32,+32)
//   -> 8 mfma_f32_16x16x32_f16 / step; acc 4x2xf32x4 = 32 VGPR.
// B regs: Bk[2][16] half8 = 128 VGPR; ~210 total -> 2 waves/SIMD.
// ---------------------------------------------------------------------------

#define TOTAL_TERMS 37449
#define NSTEP 1172
#define MBLK 32
#define KY 16
#define OUT_ELEMS 262144            // 4096*64

typedef _Float16 half8 __attribute__((ext_vector_type(8)));
typedef float f32x4 __attribute__((ext_vector_type(4)));

// Coalesced tiled transpose W (f32, n-major) -> Wt (f16 fragments).
// Fragment element (s,nt,lane,j) = W[nt*16+(lane&15)][orig(s*32+(lane>>4)*8+j)]
__global__ __launch_bounds__(256) void convert_w(const float* __restrict__ W,
                                                 const float* __restrict__ bias,
                                                 _Float16* __restrict__ Wt) {
    __shared__ _Float16 lds[64][72];
    int tid  = threadIdx.x;
    int lane = tid & 63;
    int nq   = tid >> 6;               // 0..3
    int kb   = blockIdx.x * 64;
    int kp   = kb + lane;

    int o, mode;                       // 0=load W, 1=zero, 2=const+bias
    if (kp < 8)           { o = 1 + kp;            mode = 0; }
    else if (kp == 8)     { o = 0;                 mode = 2; }
    else if (kp < 32)     { o = 0;                 mode = 1; }
    else if (kp < 96)     { o = 9    + (kp - 32);  mode = 0; }
    else if (kp < 608)    { o = 73   + (kp - 96);  mode = 0; }
    else if (kp < 4704)   { o = 585  + (kp - 608); mode = 0; }
    else if (kp < 37472)  { o = 4681 + (kp - 4704);mode = 0; }
    else                  { o = 0;                 mode = 1; }

#pragma unroll
    for (int r = 0; r < 16; ++r) {
        int n = r * 4 + nq;
        const float* wrow = W + (size_t)n * TOTAL_TERMS;
        float v;
        if (mode == 1)      v = 0.f;
        else if (mode == 2) v = wrow[0] + bias[n];
        else                v = wrow[o];             // coalesced along lane
        lds[n][lane] = (_Float16)v;
    }
    __syncthreads();

    int quad = lane >> 4, l16 = lane & 15;
    int n = nq * 16 + l16;
#pragma unroll
    for (int sl = 0; sl < 2; ++sl) {
        int kk = sl * 32 + quad * 8;
        half8 hv;
#pragma unroll
        for (int j = 0; j < 8; ++j) hv[j] = lds[n][kk + j];
        int s = (kb >> 5) + sl;
        *(half8*)(Wt + ((size_t)(s * 4 + nq) * 64 + lane) * 8) = hv;  // coalesced
    }
}

__global__ __launch_bounds__(256, 2) void poly_gemm(const float* __restrict__ z,
                                                    const _Float16* __restrict__ Wt,
                                                    float* __restrict__ part,
                                                    float* __restrict__ out,
                                                    int use_atomic) {
    __shared__ __align__(16) _Float16 zm[128][8];   // sample-major
    __shared__ _Float16 zT[8][144];                 // digit-major

    int tid  = threadIdx.x;
    int lane = tid & 63;
    int w    = tid >> 6;
    int g    = w >> 1;                 // rows [g*64, g*64+64)
    int h    = w & 1;                  // cols [h*32, h*32+32)
    int mb   = blockIdx.x;
    int ky   = blockIdx.y;             // [0, 16) -- every block is uniform

    // Per-step B bytes: 4 frags x 1024 B; this wave reads frags 2h, 2h+1.
    const char* gb  = (const char*)Wt + (size_t)((147 + 64 * ky) * 4 + 2 * h) * 1024
                    + (size_t)lane * 16;                       // deg5 slice
    const char* gb4 = (const char*)Wt + (size_t)((19 + 8 * ky) * 4 + 2 * h) * 1024
                    + (size_t)lane * 16;                       // deg4 slice

    // Prologue: prefetch deg5 group 0 (8 steps) into bank 0 BEFORE z staging
    // so its latency overlaps the z loads + barrier.
    half8 Bk[2][16];
#pragma unroll
    for (int ii = 0; ii < 8; ++ii)
#pragma unroll
        for (int k = 0; k < 2; ++k)
            Bk[0][ii * 2 + k] = *(const half8*)(gb + ii * 4096 + k * 1024);

    if (tid < 128) {
        const float* zp = z + ((size_t)(mb * 128 + tid)) * 8;
        float4 a = *(const float4*)zp;
        float4 b4 = *(const float4*)(zp + 4);
        half8 hz;
        hz[0] = (_Float16)a.x;  hz[1] = (_Float16)a.y;
        hz[2] = (_Float16)a.z;  hz[3] = (_Float16)a.w;
        hz[4] = (_Float16)b4.x; hz[5] = (_Float16)b4.y;
        hz[6] = (_Float16)b4.z; hz[7] = (_Float16)b4.w;
        *(half8*)&zm[tid][0] = hz;
#pragma unroll
        for (int j = 0; j < 8; ++j) zT[j][tid] = hz[j];
    }
    __syncthreads();

    int quad = lane >> 4;
    int l16  = lane & 15;
    int mrow[4];
    half8 zv[4];
    _Float16 zq[4], zq4[4];
#pragma unroll
    for (int t = 0; t < 4; ++t) {
        mrow[t] = g * 64 + t * 16 + l16;
        zv[t]   = *(const half8*)&zm[mrow[t]][0];
        zq[t]   = zT[quad][mrow[t]];       // z[quad]
        zq4[t]  = zT[quad + 4][mrow[t]];   // z[quad+4]
    }

    f32x4 acc[4][2];
#pragma unroll
    for (int t = 0; t < 4; ++t)
#pragma unroll
        for (int k = 0; k < 2; ++k) acc[t][k] = (f32x4){0.f, 0.f, 0.f, 0.f};

    // d1 digit for both deg5 and deg4 slices of this ky: z[ky>>1]
    _Float16 a1[4];
#pragma unroll
    for (int t = 0; t < 4; ++t) a1[t] = zT[ky >> 1][mrow[t]];

    // ---- deg5 main: 8 groups (4 sc x 2 gp), bank = group & 1 ----
    for (int sc = 0; sc < 4; ++sc) {
        int rtop = (4 * ky + sc) & 7;                  // d2 digit
        _Float16 gz[4];
#pragma unroll
        for (int t = 0; t < 4; ++t) gz[t] = a1[t] * zT[rtop][mrow[t]];
#pragma unroll
        for (int gp = 0; gp < 2; ++gp) {
            // prefetch next 8-step group into the other bank; the 9th group
            // slot fetches the deg4 slice instead of running off the end
            const char* gn = (sc == 3 && gp == 1) ? gb4 : (gb + 32768);
#pragma unroll
            for (int ii = 0; ii < 8; ++ii)
#pragma unroll
                for (int k = 0; k < 2; ++k)
                    Bk[gp ^ 1][ii * 2 + k] =
                        *(const half8*)(gn + ii * 4096 + k * 1024);
            // compute 8 steps from current bank (all indices compile-time)
#pragma unroll
            for (int ii = 0; ii < 8; ++ii) {
                const int r3 = gp * 4 + (ii >> 1);
                half8 av[4];
#pragma unroll
                for (int t = 0; t < 4; ++t) {
                    _Float16 f = gz[t] * zv[t][r3] *
                                 ((ii & 1) ? zq4[t] : zq[t]);
                    av[t] = zv[t] * f;                 // v_pk_mul_f16 x4
                }
#pragma unroll
                for (int t = 0; t < 4; ++t)
#pragma unroll
                    for (int k = 0; k < 2; ++k)
                        acc[t][k] = __builtin_amdgcn_mfma_f32_16x16x32_f16(
                            av[t], Bk[gp][ii * 2 + k], acc[t][k], 0, 0, 0);
            }
            gb += 32768;
        }
    }

    // ---- deg4 group: 8 steps from bank 0; prefetch extra-step B -> bank 1 ----
    {
        const char* ge0 = (const char*)Wt + (size_t)(ky * 4 + 2 * h) * 1024
                        + (size_t)lane * 16;           // step s = ky
        Bk[1][0] = *(const half8*)(ge0);
        Bk[1][1] = *(const half8*)(ge0 + 1024);
        if (ky < 3) {                                  // step s = 16 + ky
            const char* ge1 = (const char*)Wt
                            + (size_t)((16 + ky) * 4 + 2 * h) * 1024
                            + (size_t)lane * 16;
            Bk[1][2] = *(const half8*)(ge1);
            Bk[1][3] = *(const half8*)(ge1 + 1024);
        }
        // deg4 digits: d1 = ky>>1 (a1), d2 = (ky&1)*4 + (ii>>1),
        //              d3 = quad + 4*(ii&1), d4 = e
        const int r3b = (ky & 1) * 4;
        _Float16 d2z[4][4];                            // static-index regs
#pragma unroll
        for (int j = 0; j < 4; ++j)
#pragma unroll
            for (int t = 0; t < 4; ++t) d2z[t][j] = zT[r3b + j][mrow[t]];
#pragma unroll
        for (int ii = 0; ii < 8; ++ii) {
            half8 av[4];
#pragma unroll
            for (int t = 0; t < 4; ++t) {
                _Float16 f = a1[t] * d2z[t][ii >> 1] *
                             ((ii & 1) ? zq4[t] : zq[t]);
                av[t] = zv[t] * f;                     // v_pk_mul_f16 x4
            }
#pragma unroll
            for (int t = 0; t < 4; ++t)
#pragma unroll
                for (int k = 0; k < 2; ++k)
                    acc[t][k] = __builtin_amdgcn_mfma_f32_16x16x32_f16(
                        av[t], Bk[0][ii * 2 + k], acc[t][k], 0, 0, 0);
        }
    }

    // ---- extra low-degree step(s): s = ky, plus s = 16+ky for ky < 3 ----
    {
        half8 av[4];
        if (ky == 0) {
            // s==0: deg<=1 (z | const | zeros)
#pragma unroll
            for (int t = 0; t < 4; ++t) {
                if (quad == 0)      av[t] = zv[t];
                else if (quad == 1) { av[t] = (half8){}; av[t][0] = (_Float16)1.f; }
                else                av[t] = (half8){};
            }
        } else if (ky < 3) {
            // s=1..2: deg2
            int r1 = (ky - 1) * 4 + quad;
#pragma unroll
            for (int t = 0; t < 4; ++t) {
                _Float16 f = zT[r1][mrow[t]];
                av[t] = zv[t] * f;
            }
        } else {
            // s=3..15: deg3, u = s-3
            int u = ky - 3;
            int r1 = u >> 1, r2 = ((u & 1) << 2) + quad;
#pragma unroll
            for (int t = 0; t < 4; ++t) {
                _Float16 f = zT[r1][mrow[t]] * zT[r2][mrow[t]];
                av[t] = zv[t] * f;
            }
        }
#pragma unroll
        for (int t = 0; t < 4; ++t)
#pragma unroll
            for (int k = 0; k < 2; ++k)
                acc[t][k] = __builtin_amdgcn_mfma_f32_16x16x32_f16(
                    av[t], Bk[1][k], acc[t][k], 0, 0, 0);

        if (ky < 3) {
            // s = 16+ky: deg3, u = 13+ky
            int u = 13 + ky;
            int r1 = u >> 1, r2 = ((u & 1) << 2) + quad;
#pragma unroll
            for (int t = 0; t < 4; ++t) {
                _Float16 f = zT[r1][mrow[t]] * zT[r2][mrow[t]];
                av[t] = zv[t] * f;
            }
#pragma unroll
            for (int t = 0; t < 4; ++t)
#pragma unroll
                for (int k = 0; k < 2; ++k)
                    acc[t][k] = __builtin_amdgcn_mfma_f32_16x16x32_f16(
                        av[t], Bk[1][2 + k], acc[t][k], 0, 0, 0);
        }
    }

    // epilogue: C/D layout col=lane&15, row=(lane>>4)*4+reg
    float* dstbase = use_atomic ? out : (part + (size_t)ky * OUT_ELEMS);
#pragma unroll
    for (int t = 0; t < 4; ++t) {
        int mbase = mb * 128 + g * 64 + t * 16 + quad * 4;
#pragma unroll
        for (int k = 0; k < 2; ++k) {
            int col = h * 32 + k * 16 + l16;
#pragma unroll
            for (int r = 0; r < 4; ++r) {
                size_t idx = (size_t)(mbase + r) * 64 + col;
                if (use_atomic) unsafeAtomicAdd(out + idx, acc[t][k][r]);
                else __builtin_nontemporal_store(acc[t][k][r], dstbase + idx);
            }
        }
    }
}

// Phase 2: out[i] = sum_ky part[ky][i]  (vectorized, nontemporal)
__global__ __launch_bounds__(256) void reduce_part(const float* __restrict__ part,
                                                   float* __restrict__ out) {
    int gid = blockIdx.x * 256 + threadIdx.x;      // 65536 float4s
    const f32x4* p4 = (const f32x4*)part;
    f32x4 s = (f32x4){0.f, 0.f, 0.f, 0.f};
#pragma unroll
    for (int j = 0; j < KY; ++j)
        s += __builtin_nontemporal_load(p4 + (size_t)j * (OUT_ELEMS / 4) + gid);
    __builtin_nontemporal_store(s, ((f32x4*)out) + gid);
}

extern "C" void kernel_launch(void* const* d_in, const int* in_sizes, int n_in,
                              void* d_out, int out_size, void* d_ws, size_t ws_size,
                              hipStream_t stream) {
    (void)in_sizes; (void)n_in;
    const float* z = (const float*)d_in[0];
    const float* W = (const float*)d_in[1];
    const float* b = (const float*)d_in[2];
    float* out = (float*)d_out;

    const size_t part_bytes = (size_t)KY * OUT_ELEMS * sizeof(float);  // 16 MB
    const size_t wt_bytes   = (size_t)(NSTEP + 16) * 2048 * sizeof(_Float16);
    const bool two_phase = ws_size >= part_bytes + wt_bytes;

    float* part;
    _Float16* Wt;
    if (two_phase) {
        part = (float*)d_ws;
        Wt   = (_Float16*)((char*)d_ws + part_bytes);
    } else {
        part = out;                    // unused in atomic mode
        Wt   = (_Float16*)d_ws;
    }

    if (!two_phase)
        hipMemsetAsync(d_out, 0, (size_t)out_size * sizeof(float), stream);
    hipLaunchKernelGGL(convert_w, dim3(NSTEP / 2), dim3(256), 0, stream, W, b, Wt);
    hipLaunchKernelGGL(poly_gemm, dim3(MBLK, KY), dim3(256), 0, stream,
                       z, Wt, part, out, two_phase ? 0 : 1);
    if (two_phase)
        hipLaunchKernelGGL(reduce_part, dim3(OUT_ELEMS / 4 / 256), dim3(256), 0,
                           stream, part, out);
}